// Round 1
// baseline (214.015 us; speedup 1.0000x reference)
//
#include <hip/hip_runtime.h>
#include <math.h>

#define HALF 64
#define DFE  128
#define B    4096          // HALF*HALF
#define NF   8192          // 2*B
#define PAIR_BLOCKS 512
#define ROWS_PER_BLOCK 16  // NF / PAIR_BLOCKS

// ---------------- K1: cosine Gram for one half -> f[h*B .. h*B+B) ----------
__global__ __launch_bounds__(256) void gram_kernel(const float* __restrict__ feats,
                                                   double* __restrict__ f) {
    __shared__ float  xs[HALF][DFE];   // 32 KB raw f32 rows
    __shared__ double inv[HALF];
    const int h   = blockIdx.x;                  // 0 = src, 1 = trgt
    const int tid = threadIdx.x;
    const float* base = feats + h * HALF * DFE;

    for (int idx = tid; idx < HALF * DFE; idx += 256)
        xs[idx >> 7][idx & 127] = base[idx];
    __syncthreads();

    if (tid < HALF) {
        double s = 0.0;
        for (int k = 0; k < DFE; ++k) {
            double v = (double)xs[tid][k];
            s += v * v;
        }
        double n = sqrt(s);
        inv[tid] = 1.0 / fmax(n, 1e-8);
    }
    __syncthreads();

    for (int p = tid; p < B; p += 256) {
        const int i = p >> 6, j = p & 63;
        const double si = inv[i], sj = inv[j];
        double s = 0.0;
        for (int k = 0; k < DFE; ++k)
            s += ((double)xs[i][k] * si) * ((double)xs[j][k] * sj);
        f[h * B + p] = s;
    }
}

// ---------------- K2: c = 1/(4*D_mean), D_mean = 2*(m2 - m1^2) -------------
__global__ __launch_bounds__(256) void stats_kernel(const double* __restrict__ f,
                                                    double* __restrict__ cptr) {
    __shared__ double s1[256], s2[256];
    const int tid = threadIdx.x;
    double a1 = 0.0, a2 = 0.0;
    for (int i = tid; i < NF; i += 256) {
        double v = f[i];
        a1 += v;
        a2 += v * v;
    }
    s1[tid] = a1; s2[tid] = a2;
    __syncthreads();
    for (int off = 128; off > 0; off >>= 1) {
        if (tid < off) { s1[tid] += s1[tid + off]; s2[tid] += s2[tid + off]; }
        __syncthreads();
    }
    if (tid == 0) {
        const double m1 = s1[0] / (double)NF;
        const double m2 = s2[0] / (double)NF;
        const double Dm = 2.0 * (m2 - m1 * m1);
        cptr[0] = 1.0 / (4.0 * Dm);
    }
}

// ---------------- K3: pair sums, 16 i-rows per block -----------------------
__global__ __launch_bounds__(256) void pair_kernel(const double* __restrict__ f,
                                                   const double* __restrict__ cptr,
                                                   double* __restrict__ partials) {
    __shared__ double fs[NF];           // 64 KB (gfx950: up to 160 KB/WG)
    __shared__ double rs[256], rc[256]; // 4 KB
    const int tid = threadIdx.x;
    for (int i = tid; i < NF; i += 256) fs[i] = f[i];
    __syncthreads();

    const double c  = cptr[0];
    const int ti = tid >> 4;            // 0..15 : which i-row
    const int tj = tid & 15;            // 0..15 : j-stride offset
    const int i  = blockIdx.x * ROWS_PER_BLOCK + ti;
    const double fi   = fs[i];
    const int ihalf   = i >> 12;        // 0 or 1 (blocks never straddle halves)

    double s_same = 0.0, s_cross = 0.0;
    for (int j = tj; j < NF; j += 16) {
        if (j == i) continue;           // diagonal excluded by (1 - eye)
        const double d  = fi - fs[j];
        const double u  = exp(-(d * d) * c);
        const double u2 = u * u, u4 = u2 * u2, u8 = u4 * u4, u16 = u8 * u8;
        const double K  = u + u2 + u4 + u8 + u16;
        if ((j >> 12) == ihalf) s_same += K; else s_cross += K;
    }

    rs[tid] = s_same; rc[tid] = s_cross;
    __syncthreads();
    for (int off = 128; off > 0; off >>= 1) {
        if (tid < off) { rs[tid] += rs[tid + off]; rc[tid] += rc[tid + off]; }
        __syncthreads();
    }
    if (tid == 0) {
        partials[blockIdx.x * 2 + 0] = rs[0];
        partials[blockIdx.x * 2 + 1] = rc[0];
    }
}

// ---------------- K4: deterministic final reduce + loss --------------------
__global__ __launch_bounds__(256) void final_kernel(const double* __restrict__ partials,
                                                    float* __restrict__ out) {
    __shared__ double rs[256], rc[256];
    const int tid = threadIdx.x;
    double a = 0.0, b = 0.0;
    for (int i = tid; i < PAIR_BLOCKS; i += 256) {
        a += partials[i * 2 + 0];
        b += partials[i * 2 + 1];
    }
    rs[tid] = a; rc[tid] = b;
    __syncthreads();
    for (int off = 128; off > 0; off >>= 1) {
        if (tid < off) { rs[tid] += rs[tid + off]; rc[tid] += rc[tid + off]; }
        __syncthreads();
    }
    if (tid == 0) {
        const double S_same  = rs[0];
        const double S_cross = rc[0];
        const double bb = (double)B;
        const double loss = S_same / (bb * (bb - 1.0))
                          - S_cross / (bb * bb)
                          + 2.0 / (bb - 1.0);
        out[0] = (float)loss;
    }
}

extern "C" void kernel_launch(void* const* d_in, const int* in_sizes, int n_in,
                              void* d_out, int out_size, void* d_ws, size_t ws_size,
                              hipStream_t stream) {
    const float* feats = (const float*)d_in[0];
    float* out = (float*)d_out;
    double* ws = (double*)d_ws;

    double* f        = ws;            // 8192 doubles = 64 KB
    double* cptr     = ws + NF;       // 1 double (padded to 8)
    double* partials = ws + NF + 8;   // 1024 doubles = 8 KB

    gram_kernel <<<2,            256, 0, stream>>>(feats, f);
    stats_kernel<<<1,            256, 0, stream>>>(f, cptr);
    pair_kernel <<<PAIR_BLOCKS,  256, 0, stream>>>(f, cptr, partials);
    final_kernel<<<1,            256, 0, stream>>>(partials, out);
}

// Round 2
// 59.493 us; speedup vs baseline: 3.5973x; 3.5973x over previous
//
#include <hip/hip_runtime.h>
#include <math.h>

#define HALF 64
#define DFE  128
#define B    4096          // HALF*HALF
#define NF   8192          // 2*B
#define SAME_BLOCKS  512   // 8192 rows / 16
#define CROSS_BLOCKS 512   // 4096 rows / 16 * 2 j-halves
#define PAIR_BLOCKS  (SAME_BLOCKS + CROSS_BLOCKS)

// ---- fast f64 exp: returns 2^y for y <= 0 (caller pre-multiplies by log2e)
// accuracy ~7e-12 rel (degree-9 Taylor of e^w, |w| <= 0.347)
__device__ __forceinline__ double exp2_fast(double y) {
    const double rn = rint(y);
    const double r  = y - rn;                       // [-0.5, 0.5]
    const double w  = r * 0.69314718055994530942;   // r*ln2
    double p  = 2.7557319223985890653e-6;           // 1/9!
    p = fma(p, w, 2.4801587301587301587e-5);        // 1/8!
    p = fma(p, w, 1.9841269841269841270e-4);        // 1/7!
    p = fma(p, w, 1.3888888888888888889e-3);        // 1/6!
    p = fma(p, w, 8.3333333333333333333e-3);        // 1/5!
    p = fma(p, w, 4.1666666666666666667e-2);        // 1/4!
    p = fma(p, w, 1.6666666666666666667e-1);        // 1/3!
    p = fma(p, w, 0.5);
    p = fma(p, w, 1.0);
    p = fma(p, w, 1.0);
    const int ni = (int)rn;                          // n in [-34, 0]
    const double s = __longlong_as_double(((long long)(ni + 1023)) << 52);
    return p * s;
}

__device__ __forceinline__ double kern5(double d, double cc) {
    const double u  = exp2_fast(d * d * cc);  // u = exp(-D/(4*Dm))
    const double u2 = u * u, u4 = u2 * u2, u8 = u4 * u4;
    return ((u + u2) + (u4 + u8)) + u8 * u8;  // u + u^2 + u^4 + u^8 + u^16
}

// ---------------- K1: cosine Gram, 16 blocks per half ----------------------
__global__ __launch_bounds__(256) void gram_kernel(const float* __restrict__ feats,
                                                   double* __restrict__ f) {
    __shared__ float  xs[HALF][DFE];   // 32 KB
    __shared__ double inv[HALF];
    const int h   = blockIdx.x >> 4;   // which half
    const int seg = blockIdx.x & 15;   // which 256-entry slice of the 4096 outputs
    const int tid = threadIdx.x;
    const float* base = feats + h * HALF * DFE;

    for (int idx = tid; idx < HALF * DFE; idx += 256)
        xs[idx >> 7][idx & 127] = base[idx];
    __syncthreads();

    if (tid < HALF) {
        double s = 0.0;
        for (int k = 0; k < DFE; ++k) {
            const double v = (double)xs[tid][k];
            s += v * v;
        }
        inv[tid] = 1.0 / fmax(sqrt(s), 1e-8);
    }
    __syncthreads();

    const int p = seg * 256 + tid;
    const int i = p >> 6, j = p & 63;
    double s0 = 0.0, s1 = 0.0;
    for (int k = 0; k < DFE; k += 2) {        // 2 chains for ILP
        s0 += (double)xs[i][k]     * (double)xs[j][k];
        s1 += (double)xs[i][k + 1] * (double)xs[j][k + 1];
    }
    f[h * B + p] = (s0 + s1) * inv[i] * inv[j];
}

// ---------------- K2: cc = -log2(e)/(4*D_mean), D_mean = 2*(m2-m1^2) -------
__global__ __launch_bounds__(256) void stats_kernel(const double* __restrict__ f,
                                                    double* __restrict__ ccp) {
    __shared__ double s1[256], s2[256];
    const int tid = threadIdx.x;
    double a1 = 0.0, a2 = 0.0;
    for (int i = tid; i < NF; i += 256) {
        const double v = f[i];
        a1 += v;
        a2 += v * v;
    }
    s1[tid] = a1; s2[tid] = a2;
    __syncthreads();
    for (int off = 128; off > 0; off >>= 1) {
        if (tid < off) { s1[tid] += s1[tid + off]; s2[tid] += s2[tid + off]; }
        __syncthreads();
    }
    if (tid == 0) {
        const double m1 = s1[0] / (double)NF;
        const double m2 = s2[0] / (double)NF;
        const double Dm = 2.0 * (m2 - m1 * m1);
        ccp[0] = -1.4426950408889634074 / (4.0 * Dm);
    }
}

// ---------------- K3: unordered pair sums --------------------------------
// blocks [0,512):   same-half unordered pairs via cyclic distance trick
// blocks [512,1024): src x trgt rectangle, split into two j-halves
__global__ __launch_bounds__(256, 4) void pair_kernel(const double* __restrict__ f,
                                                      const double* __restrict__ ccp,
                                                      double* __restrict__ partials) {
    __shared__ double fs[B];       // 32 KB: one half of f
    __shared__ double red[256];    // 2 KB
    const int tid = threadIdx.x;
    const int bid = blockIdx.x;
    const int ti  = tid >> 4;      // 0..15: which i-row of this block
    const int tj  = tid & 15;      // 0..15: j/k stride offset
    const double cc = ccp[0];
    double acc = 0.0;

    if (bid < SAME_BLOCKS) {
        const int ig = bid * 16 + ti;          // global row 0..8191
        const int h  = ig >> 12;               // half (blocks never straddle)
        const int il = ig & 4095;              // row within half
        const double* fh = f + (h << 12);
        for (int idx = tid; idx < B; idx += 256) fs[idx] = fh[idx];
        __syncthreads();
        const double fi = fs[il];
        // cyclic distances 1..2047: each unordered pair exactly once
        #pragma unroll 2
        for (int k = 1 + tj; k <= 2047; k += 16) {
            const int j = (il + k) & 4095;
            acc += kern5(fi - fs[j], cc);
        }
        // distance exactly 2048: once per pair
        if (tj == 0 && il < 2048)
            acc += kern5(fi - fs[il + 2048], cc);
    } else {
        const int bc = bid - SAME_BLOCKS;      // 0..511
        const int i  = (bc >> 1) * 16 + ti;    // src row 0..4095
        const int j0 = (bc & 1) * 2048;        // which j-half
        const double* ft = f + B;              // trgt half
        for (int idx = tid; idx < B; idx += 256) fs[idx] = ft[idx];
        __syncthreads();
        const double fi = f[i];
        #pragma unroll 2
        for (int m = 0; m < 128; ++m) {
            const int j = j0 + tj + (m << 4);
            acc += kern5(fi - fs[j], cc);
        }
    }

    red[tid] = acc;
    __syncthreads();
    for (int off = 128; off > 0; off >>= 1) {
        if (tid < off) red[tid] += red[tid + off];
        __syncthreads();
    }
    if (tid == 0) partials[bid] = red[0];
}

// ---------------- K4: deterministic final reduce + loss --------------------
__global__ __launch_bounds__(256) void final_kernel(const double* __restrict__ partials,
                                                    float* __restrict__ out) {
    __shared__ double rs[256], rc[256];
    const int tid = threadIdx.x;
    double a = 0.0, b = 0.0;
    for (int i = tid; i < SAME_BLOCKS; i += 256)  a += partials[i];
    for (int i = tid; i < CROSS_BLOCKS; i += 256) b += partials[SAME_BLOCKS + i];
    rs[tid] = a; rc[tid] = b;
    __syncthreads();
    for (int off = 128; off > 0; off >>= 1) {
        if (tid < off) { rs[tid] += rs[tid + off]; rc[tid] += rc[tid + off]; }
        __syncthreads();
    }
    if (tid == 0) {
        const double S_same  = 2.0 * rs[0];   // unordered -> ordered
        const double S_cross = 2.0 * rc[0];   // one direction -> both
        const double bb = (double)B;
        const double loss = S_same / (bb * (bb - 1.0))
                          - S_cross / (bb * bb)
                          + 2.0 / (bb - 1.0);
        out[0] = (float)loss;
    }
}

extern "C" void kernel_launch(void* const* d_in, const int* in_sizes, int n_in,
                              void* d_out, int out_size, void* d_ws, size_t ws_size,
                              hipStream_t stream) {
    const float* feats = (const float*)d_in[0];
    float* out = (float*)d_out;
    double* ws = (double*)d_ws;

    double* f        = ws;            // 8192 doubles = 64 KB
    double* ccp      = ws + NF;       // 1 double (padded to 8)
    double* partials = ws + NF + 8;   // 1024 doubles

    gram_kernel <<<32,           256, 0, stream>>>(feats, f);
    stats_kernel<<<1,            256, 0, stream>>>(f, ccp);
    pair_kernel <<<PAIR_BLOCKS,  256, 0, stream>>>(f, ccp, partials);
    final_kernel<<<1,            256, 0, stream>>>(partials, out);
}

// Round 3
// 46.741 us; speedup vs baseline: 4.5787x; 1.2728x over previous
//
#include <hip/hip_runtime.h>
#include <math.h>

#define HALF 64
#define DFE  128
#define B    4096          // HALF*HALF
#define NF   8192          // 2*B
#define GRAM_BLOCKS  32
#define SAME_BLOCKS  512
#define CROSS_BLOCKS 512
#define PAIR_BLOCKS  (SAME_BLOCKS + CROSS_BLOCKS)
#define LOG2E 1.4426950408889634074

// K(u)=u+u^2+u^4+u^8+u^16 with u=2^{-(d*d)}, d pre-scaled by sqrt(log2e/(4*Dm)).
// exp2 via magic-shifter range reduction + degree-8 Taylor (rel err ~2e-10).
__device__ __forceinline__ void kern_acc(double d, double& a1, double& a2, double& a3) {
    const double SHIFT = 6755399441055744.0;     // 1.5 * 2^52
    const double tt = fma(d, -d, SHIFT);         // nearest-int(-d^2) + SHIFT
    const double nf = tt - SHIFT;                // n as double
    const double r  = fma(d, -d, -nf);           // exact -d^2 - n, in [-0.5, 0.5]
    const int    ni = (int)__double_as_longlong(tt);  // low 32 bits = n
    double p  = 1.32154867901443095e-06;         // (ln2)^8/8!
    p = fma(p, r, 1.52527338040598403e-05);
    p = fma(p, r, 1.54035303933816099e-04);
    p = fma(p, r, 1.33335581464284434e-03);
    p = fma(p, r, 9.61812910762847716e-03);
    p = fma(p, r, 5.55041086648215930e-02);
    p = fma(p, r, 2.40226506959100694e-01);
    p = fma(p, r, 6.93147180559945286e-01);
    p = fma(p, r, 1.0);
    const double sc = __longlong_as_double(((long long)(ni + 1023)) << 52);
    const double u  = p * sc;
    const double u2 = u * u, u4 = u2 * u2, u8 = u4 * u4;
    a1 += (u + u2);
    a2 += (u4 + u8);
    a3  = fma(u8, u8, a3);                       // + u^16
}

// ---------------- K1: cosine Gram + moment partials ------------------------
__global__ __launch_bounds__(256) void gram_kernel(const float* __restrict__ feats,
                                                   double* __restrict__ f,
                                                   double* __restrict__ pm) {
    __shared__ float  xs[HALF][DFE];        // 32 KB
    __shared__ double xd[HALF][DFE + 1];    // 64.5 KB, padded: conflict-free j-reads
    __shared__ double inv[HALF];
    __shared__ double red1[256], red2[256];
    const int h   = blockIdx.x >> 4;
    const int seg = blockIdx.x & 15;
    const int tid = threadIdx.x;
    const float* base = feats + h * HALF * DFE;

    for (int idx = tid; idx < HALF * DFE; idx += 256)
        xs[idx >> 7][idx & 127] = base[idx];
    __syncthreads();

    if (tid < HALF) {
        double s0 = 0, s1 = 0, s2 = 0, s3 = 0;
        for (int k = 0; k < DFE; k += 4) {
            const double v0 = xs[tid][k],     v1 = xs[tid][k + 1];
            const double v2 = xs[tid][k + 2], v3 = xs[tid][k + 3];
            s0 = fma(v0, v0, s0); s1 = fma(v1, v1, s1);
            s2 = fma(v2, v2, s2); s3 = fma(v3, v3, s3);
        }
        inv[tid] = 1.0 / fmax(sqrt((s0 + s1) + (s2 + s3)), 1e-8);
    }
    __syncthreads();

    for (int idx = tid; idx < HALF * DFE; idx += 256) {
        const int i = idx >> 7, k = idx & 127;
        xd[i][k] = (double)xs[i][k] * inv[i];
    }
    __syncthreads();

    const int p = seg * 256 + tid;
    const int i = p >> 6, j = p & 63;      // i wave-uniform, j per-lane
    double s0 = 0, s1 = 0, s2 = 0, s3 = 0;
    for (int k = 0; k < DFE; k += 4) {
        s0 = fma(xd[i][k],     xd[j][k],     s0);
        s1 = fma(xd[i][k + 1], xd[j][k + 1], s1);
        s2 = fma(xd[i][k + 2], xd[j][k + 2], s2);
        s3 = fma(xd[i][k + 3], xd[j][k + 3], s3);
    }
    const double v = (s0 + s1) + (s2 + s3);
    f[h * B + p] = v;

    red1[tid] = v; red2[tid] = v * v;
    __syncthreads();
    for (int off = 128; off > 0; off >>= 1) {
        if (tid < off) { red1[tid] += red1[tid + off]; red2[tid] += red2[tid + off]; }
        __syncthreads();
    }
    if (tid == 0) {
        pm[2 * blockIdx.x]     = red1[0];
        pm[2 * blockIdx.x + 1] = red2[0];
    }
}

// ---------------- K2: unordered pair sums ----------------------------------
__global__ __launch_bounds__(256, 4) void pair_kernel(const double* __restrict__ f,
                                                      const double* __restrict__ pm,
                                                      double* __restrict__ partials) {
    __shared__ double fs[B];       // 32 KB: one half of f, pre-scaled
    __shared__ double red[256];
    const int tid = threadIdx.x;
    const int bid = blockIdx.x;
    const int ti  = tid >> 4;
    const int tj  = tid & 15;

    // cc from gram moment partials (uniform scalar loads, fixed order)
    double s1 = 0.0, s2 = 0.0;
    #pragma unroll
    for (int q = 0; q < GRAM_BLOCKS; ++q) { s1 += pm[2 * q]; s2 += pm[2 * q + 1]; }
    const double m1  = s1 * (1.0 / NF);
    const double m2  = s2 * (1.0 / NF);
    const double Dm  = 2.0 * (m2 - m1 * m1);
    const double scl = sqrt(LOG2E / (4.0 * Dm));

    double a1 = 0.0, a2 = 0.0, a3 = 0.0;

    if (bid < SAME_BLOCKS) {
        const int ig = bid * 16 + ti;          // global row (blocks never straddle)
        const int h  = ig >> 12;
        const int il = ig & 4095;
        const double* fh = f + (h << 12);
        for (int idx = tid; idx < B; idx += 256) fs[idx] = fh[idx] * scl;
        __syncthreads();
        const double fi = fs[il];
        // cyclic distances: k = 1+tj+16m, m=0..126 always valid (k<=2032)
        #pragma unroll 4
        for (int m = 0; m < 127; ++m) {
            const int j = (il + 1 + tj + (m << 4)) & 4095;
            kern_acc(fi - fs[j], a1, a2, a3);
        }
        {   // m=127: k = 2033+tj, valid for tj<=14
            const int k = 2033 + tj;
            if (k <= 2047) kern_acc(fi - fs[(il + k) & 4095], a1, a2, a3);
        }
        if (tj == 0 && il < 2048)              // distance exactly 2048, once
            kern_acc(fi - fs[il + 2048], a1, a2, a3);
    } else {
        const int bc = bid - SAME_BLOCKS;
        const int i  = (bc >> 1) * 16 + ti;    // src row
        const int j0 = (bc & 1) << 11;         // j-half of trgt
        const double* ft = f + B;
        for (int idx = tid; idx < B; idx += 256) fs[idx] = ft[idx] * scl;
        __syncthreads();
        const double fi = f[i] * scl;
        #pragma unroll 4
        for (int m = 0; m < 128; ++m)
            kern_acc(fi - fs[j0 + tj + (m << 4)], a1, a2, a3);
    }

    red[tid] = (a1 + a2) + a3;
    __syncthreads();
    for (int off = 128; off > 0; off >>= 1) {
        if (tid < off) red[tid] += red[tid + off];
        __syncthreads();
    }
    if (tid == 0) partials[bid] = red[0];
}

// ---------------- K3: deterministic final reduce + loss --------------------
__global__ __launch_bounds__(256) void final_kernel(const double* __restrict__ partials,
                                                    float* __restrict__ out) {
    __shared__ double rs[256], rc[256];
    const int tid = threadIdx.x;
    double a = 0.0, b = 0.0;
    for (int i = tid; i < SAME_BLOCKS; i += 256)  a += partials[i];
    for (int i = tid; i < CROSS_BLOCKS; i += 256) b += partials[SAME_BLOCKS + i];
    rs[tid] = a; rc[tid] = b;
    __syncthreads();
    for (int off = 128; off > 0; off >>= 1) {
        if (tid < off) { rs[tid] += rs[tid + off]; rc[tid] += rc[tid + off]; }
        __syncthreads();
    }
    if (tid == 0) {
        const double S_same  = 2.0 * rs[0];   // unordered -> ordered
        const double S_cross = 2.0 * rc[0];   // one direction -> both
        const double bb = (double)B;
        const double loss = S_same / (bb * (bb - 1.0))
                          - S_cross / (bb * bb)
                          + 2.0 / (bb - 1.0);
        out[0] = (float)loss;
    }
}

extern "C" void kernel_launch(void* const* d_in, const int* in_sizes, int n_in,
                              void* d_out, int out_size, void* d_ws, size_t ws_size,
                              hipStream_t stream) {
    const float* feats = (const float*)d_in[0];
    float* out = (float*)d_out;
    double* ws = (double*)d_ws;

    double* f        = ws;            // 8192 doubles
    double* pm       = ws + NF;       // 64 doubles (32 blocks x {sum, sumsq})
    double* partials = ws + NF + 64;  // 1024 doubles

    gram_kernel <<<GRAM_BLOCKS, 256, 0, stream>>>(feats, f, pm);
    pair_kernel <<<PAIR_BLOCKS, 256, 0, stream>>>(f, pm, partials);
    final_kernel<<<1,           256, 0, stream>>>(partials, out);
}

// Round 4
// 30.015 us; speedup vs baseline: 7.1302x; 1.5572x over previous
//
#include <hip/hip_runtime.h>
#include <math.h>

#define HALF 64
#define DFE  128
#define B    4096          // HALF*HALF
#define NF   8192          // 2*B
#define GRAM_BLOCKS  32
#define SAME_BLOCKS  512
#define CROSS_BLOCKS 512
#define PAIR_BLOCKS  (SAME_BLOCKS + CROSS_BLOCKS)
#define LOG2E 1.4426950408889634074

// K(u)=u+u^2+u^4+u^8+u^16, u=2^{-(d*d)}; d pre-scaled by sqrt(log2e/(4*Dm)).
// Hardware v_exp_f32; all-f32 pair math (error analysis: random part
// sqrt(N)-suppressed and /b^2; exp bias cancels in S_same - S_cross).
__device__ __forceinline__ void kern_acc(float d, float& a1, float& a2, float& a3) {
    const float u  = __builtin_amdgcn_exp2f(-d * d);
    const float u2 = u * u, u4 = u2 * u2, u8 = u4 * u4;
    a1 += (u + u2);
    a2 += (u4 + u8);
    a3  = fmaf(u8, u8, a3);                  // + u^16
}

// ---------------- K1: cosine Gram (f64) -> f32 f + f64 moment partials -----
__global__ __launch_bounds__(256) void gram_kernel(const float* __restrict__ feats,
                                                   float* __restrict__ ff,
                                                   double* __restrict__ pm) {
    __shared__ float  xs[HALF][DFE];        // 32 KB
    __shared__ double xd[HALF][DFE + 1];    // padded: conflict-free j-reads
    __shared__ double inv[HALF];
    __shared__ double red1[256], red2[256];
    const int h   = blockIdx.x >> 4;
    const int seg = blockIdx.x & 15;
    const int tid = threadIdx.x;
    const float* base = feats + h * HALF * DFE;

    for (int idx = tid; idx < HALF * DFE; idx += 256)
        xs[idx >> 7][idx & 127] = base[idx];
    __syncthreads();

    if (tid < HALF) {
        double s0 = 0, s1 = 0, s2 = 0, s3 = 0;
        for (int k = 0; k < DFE; k += 4) {
            const double v0 = xs[tid][k],     v1 = xs[tid][k + 1];
            const double v2 = xs[tid][k + 2], v3 = xs[tid][k + 3];
            s0 = fma(v0, v0, s0); s1 = fma(v1, v1, s1);
            s2 = fma(v2, v2, s2); s3 = fma(v3, v3, s3);
        }
        inv[tid] = 1.0 / fmax(sqrt((s0 + s1) + (s2 + s3)), 1e-8);
    }
    __syncthreads();

    for (int idx = tid; idx < HALF * DFE; idx += 256) {
        const int i = idx >> 7, k = idx & 127;
        xd[i][k] = (double)xs[i][k] * inv[i];
    }
    __syncthreads();

    const int p = seg * 256 + tid;
    const int i = p >> 6, j = p & 63;      // i wave-uniform, j per-lane
    double s0 = 0, s1 = 0, s2 = 0, s3 = 0;
    for (int k = 0; k < DFE; k += 4) {
        s0 = fma(xd[i][k],     xd[j][k],     s0);
        s1 = fma(xd[i][k + 1], xd[j][k + 1], s1);
        s2 = fma(xd[i][k + 2], xd[j][k + 2], s2);
        s3 = fma(xd[i][k + 3], xd[j][k + 3], s3);
    }
    const double v = (s0 + s1) + (s2 + s3);
    ff[h * B + p] = (float)v;              // f32 for the pair phase

    red1[tid] = v; red2[tid] = v * v;      // moments stay f64-accurate
    __syncthreads();
    for (int off = 128; off > 0; off >>= 1) {
        if (tid < off) { red1[tid] += red1[tid + off]; red2[tid] += red2[tid + off]; }
        __syncthreads();
    }
    if (tid == 0) {
        pm[2 * blockIdx.x]     = red1[0];
        pm[2 * blockIdx.x + 1] = red2[0];
    }
}

// ---------------- K2: unordered pair sums, all-f32 hot loop ----------------
__global__ __launch_bounds__(256, 4) void pair_kernel(const float* __restrict__ ff,
                                                      const double* __restrict__ pm,
                                                      double* __restrict__ partials) {
    __shared__ float  fs[B];       // 16 KB: one half of f, pre-scaled f32
    __shared__ double red[256];
    const int tid = threadIdx.x;
    const int bid = blockIdx.x;
    const int ti  = tid >> 4;
    const int tj  = tid & 15;

    // scl from gram moment partials (uniform loads, fixed order, f64)
    double s1 = 0.0, s2 = 0.0;
    #pragma unroll
    for (int q = 0; q < GRAM_BLOCKS; ++q) { s1 += pm[2 * q]; s2 += pm[2 * q + 1]; }
    const double m1 = s1 * (1.0 / NF);
    const double m2 = s2 * (1.0 / NF);
    const double Dm = 2.0 * (m2 - m1 * m1);
    const float scl = (float)sqrt(LOG2E / (4.0 * Dm));

    float a1 = 0.0f, a2 = 0.0f, a3 = 0.0f;

    if (bid < SAME_BLOCKS) {
        const int ig = bid * 16 + ti;          // global row (blocks never straddle)
        const int h  = ig >> 12;
        const int il = ig & 4095;
        const float4* fh4 = (const float4*)(ff + (h << 12));
        float4* fs4 = (float4*)fs;
        #pragma unroll
        for (int t = 0; t < 4; ++t) {          // 4 float4 loads in flight
            const int idx = tid + 256 * t;
            float4 v = fh4[idx];
            v.x *= scl; v.y *= scl; v.z *= scl; v.w *= scl;
            fs4[idx] = v;
        }
        __syncthreads();
        const float fi = fs[il];
        // cyclic distances: k = 1+tj+16m, m=0..126 always valid (k<=2032)
        #pragma unroll 4
        for (int m = 0; m < 127; ++m) {
            const int j = (il + 1 + tj + (m << 4)) & 4095;
            kern_acc(fi - fs[j], a1, a2, a3);
        }
        {   // m=127: k = 2033+tj, valid for tj<=14
            const int k = 2033 + tj;
            if (k <= 2047) kern_acc(fi - fs[(il + k) & 4095], a1, a2, a3);
        }
        if (tj == 0 && il < 2048)              // distance exactly 2048, once
            kern_acc(fi - fs[il + 2048], a1, a2, a3);
    } else {
        const int bc = bid - SAME_BLOCKS;
        const int i  = (bc >> 1) * 16 + ti;    // src row
        const int j0 = (bc & 1) << 11;         // j-half of trgt
        const float4* ft4 = (const float4*)(ff + B);
        float4* fs4 = (float4*)fs;
        #pragma unroll
        for (int t = 0; t < 4; ++t) {
            const int idx = tid + 256 * t;
            float4 v = ft4[idx];
            v.x *= scl; v.y *= scl; v.z *= scl; v.w *= scl;
            fs4[idx] = v;
        }
        __syncthreads();
        const float fi = ff[i] * scl;
        #pragma unroll 4
        for (int m = 0; m < 128; ++m)
            kern_acc(fi - fs[j0 + tj + (m << 4)], a1, a2, a3);
    }

    red[tid] = ((double)a1 + (double)a2) + (double)a3;
    __syncthreads();
    for (int off = 128; off > 0; off >>= 1) {
        if (tid < off) red[tid] += red[tid + off];
        __syncthreads();
    }
    if (tid == 0) partials[bid] = red[0];
}

// ---------------- K3: deterministic final reduce + loss --------------------
__global__ __launch_bounds__(256) void final_kernel(const double* __restrict__ partials,
                                                    float* __restrict__ out) {
    __shared__ double rs[256], rc[256];
    const int tid = threadIdx.x;
    double a = 0.0, b = 0.0;
    for (int i = tid; i < SAME_BLOCKS; i += 256)  a += partials[i];
    for (int i = tid; i < CROSS_BLOCKS; i += 256) b += partials[SAME_BLOCKS + i];
    rs[tid] = a; rc[tid] = b;
    __syncthreads();
    for (int off = 128; off > 0; off >>= 1) {
        if (tid < off) { rs[tid] += rs[tid + off]; rc[tid] += rc[tid + off]; }
        __syncthreads();
    }
    if (tid == 0) {
        const double S_same  = 2.0 * rs[0];   // unordered -> ordered
        const double S_cross = 2.0 * rc[0];   // one direction -> both
        const double bb = (double)B;
        const double loss = S_same / (bb * (bb - 1.0))
                          - S_cross / (bb * bb)
                          + 2.0 / (bb - 1.0);
        out[0] = (float)loss;
    }
}

extern "C" void kernel_launch(void* const* d_in, const int* in_sizes, int n_in,
                              void* d_out, int out_size, void* d_ws, size_t ws_size,
                              hipStream_t stream) {
    const float* feats = (const float*)d_in[0];
    float* out = (float*)d_out;
    double* ws = (double*)d_ws;

    double* pm       = ws;                         // 64 doubles
    double* partials = ws + 64;                    // 1024 doubles
    float*  ff       = (float*)(ws + 64 + 1024);   // 8192 floats

    gram_kernel <<<GRAM_BLOCKS, 256, 0, stream>>>(feats, ff, pm);
    pair_kernel <<<PAIR_BLOCKS, 256, 0, stream>>>(ff, pm, partials);
    final_kernel<<<1,           256, 0, stream>>>(partials, out);
}